// Round 11
// baseline (200.309 us; speedup 1.0000x reference)
//
#include <hip/hip_runtime.h>

typedef unsigned short u16;
typedef unsigned int u32;
typedef unsigned char u8;

typedef __attribute__((ext_vector_type(8))) short short8;   // 8 bf16
typedef __attribute__((ext_vector_type(4))) float f32x4;

// B=4, NA=NB=2048, IN=128, H=8, DH=16, C=128, OUT=128
// Inputs fp32; mask 32-bit words (kdet-detected); OUTPUT fp32.

__device__ __forceinline__ u16 f2bf(float f){
  u32 u = __float_as_uint(f);
  u += 0x7fff + ((u >> 16) & 1);   // RNE
  return (u16)(u >> 16);
}

__global__ __launch_bounds__(256) void kzero(float* __restrict__ out){
  out[blockIdx.x * 256 + threadIdx.x] = 0.f;
}

// ---------------- mask encoding detect ----------------
// flags[0]=Fm: 0 = 32-bit words (int32 0/1 or fp32 1.0), 1 = bytes, 2 = halfwords
__global__ __launch_bounds__(256) void kdet(const u32* __restrict__ mw, int* __restrict__ flags){
  __shared__ int allw, allhw, allbyte;
  int t = threadIdx.x;
  if (t == 0){ allw = 1; allhw = 1; allbyte = 1; }
  __syncthreads();
  int aw = 1, ah = 1, ab = 1;
  #pragma unroll
  for (int j = 0; j < 4; ++j){
    u32 m = mw[t + 256 * j];
    if (!(m == 0u || m == 1u || m == 0x3F800000u)) aw = 0;
    u32 lo = m & 0xFFFFu, hi = m >> 16;
    if (!((lo == 0u || lo == 1u || lo == 0x3F80u) && (hi == 0u || hi == 1u || hi == 0x3F80u))) ah = 0;
    if (m & ~0x01010101u) ab = 0;
  }
  if (!aw) atomicAnd(&allw, 0);
  if (!ah) atomicAnd(&allhw, 0);
  if (!ab) atomicAnd(&allbyte, 0);
  __syncthreads();
  if (t == 0){
    int fm = 0;
    if (allw) fm = 0; else if (allbyte) fm = 1; else if (allhw) fm = 2;
    flags[0] = fm;
  }
}

// ---------------- mask -> packed bits ----------------
// Mb[(b*2048+n)*64 + w] bit j = mask element w*32+j of row n.
__global__ __launch_bounds__(256) void kmask(const void* __restrict__ maskv,
                                             const int* __restrict__ flags,
                                             u32* __restrict__ Mb){
  int Fm = flags[0];
  int t = threadIdx.x;
  if (Fm == 0){
    int lane = t & 63;
    int wid = blockIdx.x * 4 + (t >> 6);       // 8192 waves
    const u32* mw = (const u32*)maskv;
    size_t base = (size_t)wid * 2048;          // 32 iters x 64 words
    #pragma unroll 4
    for (int i = 0; i < 32; ++i){
      u32 v = mw[base + i * 64 + lane];
      unsigned long long bal = __ballot(v != 0u);
      if (lane < 2) Mb[(base + i * 64) / 32 + lane] = (u32)(bal >> (32 * lane));
    }
    return;
  }
  int oid = blockIdx.x * 256 + t;              // one packed word per thread
  u32 bits = 0;
  if (Fm == 1){
    const uint4* mp = (const uint4*)maskv + (size_t)oid * 2;
    #pragma unroll
    for (int k = 0; k < 2; ++k){
      uint4 v = mp[k];
      u32 w[4] = {v.x, v.y, v.z, v.w};
      #pragma unroll
      for (int q = 0; q < 4; ++q)
        #pragma unroll
        for (int bb = 0; bb < 4; ++bb)
          bits |= ((w[q] >> (8*bb)) & 255u ? 1u : 0u) << (k*16 + q*4 + bb);
    }
  } else {
    const uint4* mp = (const uint4*)maskv + (size_t)oid * 4;
    #pragma unroll
    for (int k = 0; k < 4; ++k){
      uint4 v = mp[k];
      u32 w[4] = {v.x, v.y, v.z, v.w};
      #pragma unroll
      for (int q = 0; q < 4; ++q){
        bits |= ((w[q] & 0xFFFFu) ? 1u : 0u) << (k*8 + q*2);
        bits |= ((w[q] >> 16)     ? 1u : 0u) << (k*8 + q*2 + 1);
      }
    }
  }
  Mb[oid] = bits;
}

// ---------------- fold weights ----------------
__global__ __launch_bounds__(256) void kfold(const float* __restrict__ WA, const float* __restrict__ WAb,
                                             const float* __restrict__ WB, const float* __restrict__ WBb,
                                             const float* __restrict__ aAw, const float* __restrict__ aAb,
                                             const float* __restrict__ aBw, const float* __restrict__ aBb,
                                             const float* __restrict__ W,
                                             float* __restrict__ WfB, float* __restrict__ WtO,
                                             float* __restrict__ vA, float* __restrict__ vB,
                                             float* __restrict__ cA, float* __restrict__ cB){
  int gid = blockIdx.x, t = threadIdx.x;
  if (gid < 64){
    int idx = gid * 256 + t;
    int k = idx >> 7, c = idx & 127;
    WfB[idx] = WB[(c >> 4) * 2048 + k * 16 + (c & 15)];
  } else if (gid < 128){
    int idx = (gid - 64) * 256 + t;
    int c = idx >> 7, o = idx & 127;
    WtO[idx] = W[o * 128 + c];
  } else {
    int h = gid - 128;
    if (t < 128){
      float s = 0.f;
      #pragma unroll
      for (int d = 0; d < 16; ++d) s += WA[h * 2048 + t * 16 + d] * aAw[h * 16 + d];
      vA[h * 128 + t] = s;
    } else {
      int i = t - 128;
      float s = 0.f;
      #pragma unroll
      for (int d = 0; d < 16; ++d) s += WB[h * 2048 + i * 16 + d] * aBw[h * 16 + d];
      vB[h * 128 + i] = s;
    }
    if (t == 0){
      float s = aAb[h];
      #pragma unroll
      for (int d = 0; d < 16; ++d) s += WAb[h * 16 + d] * aAw[h * 16 + d];
      cA[h] = s;
    }
    if (t == 255){
      float s = aBb[h];
      #pragma unroll
      for (int d = 0; d < 16; ++d) s += WBb[h * 16 + d] * aBw[h * 16 + d];
      cB[h] = s;
    }
  }
}

// ---------------- projection: zT[b*128+c][m] (bf16) = (hB @ WfB + bias)^T ----------------
__global__ __launch_bounds__(256) void kproj(const float* __restrict__ hB,
                                             const float* __restrict__ WfB,
                                             const float* __restrict__ bB,
                                             u16* __restrict__ zT){
  __shared__ float h_l[32 * 132];
  __shared__ float W_l[64 * 128];
  __shared__ float T[128 * 33];
  int R0 = blockIdx.x * 32;
  int t = threadIdx.x;

  for (int j = 0; j < 4; ++j){
    int idx4 = t + 256 * j;
    int r = idx4 >> 5, k0 = (idx4 & 31) * 4;
    *(float4*)&h_l[r * 132 + k0] = *(const float4*)&hB[(size_t)(R0 + r) * 128 + k0];
  }

  int cg = t & 15, rg = t >> 4;
  float acc[2][8];
  for (int i = 0; i < 2; ++i) for (int s = 0; s < 8; ++s) acc[i][s] = 0.f;

  for (int kc = 0; kc < 2; ++kc){
    __syncthreads();
    for (int j = 0; j < 8; ++j){
      int idx4 = t + 256 * j;
      int k = idx4 >> 5, c0 = (idx4 & 31) * 4;
      *(float4*)&W_l[k * 128 + c0] = *(const float4*)&WfB[(kc * 64 + k) * 128 + c0];
    }
    __syncthreads();
    for (int k = 0; k < 64; ++k){
      int kk = kc * 64 + k;
      float4 w0 = *(const float4*)&W_l[k * 128 + cg * 8];
      float4 w1 = *(const float4*)&W_l[k * 128 + cg * 8 + 4];
      float wv[8] = {w0.x, w0.y, w0.z, w0.w, w1.x, w1.y, w1.z, w1.w};
      #pragma unroll
      for (int i = 0; i < 2; ++i){
        float hv = h_l[(rg * 2 + i) * 132 + kk];
        #pragma unroll
        for (int s = 0; s < 8; ++s) acc[i][s] = fmaf(hv, wv[s], acc[i][s]);
      }
    }
  }

  for (int i = 0; i < 2; ++i)
    #pragma unroll
    for (int s = 0; s < 8; ++s)
      T[(cg * 8 + s) * 33 + rg * 2 + i] = acc[i][s] + bB[cg * 8 + s];
  __syncthreads();

  int c = t >> 1, mh = (t & 1) * 16;
  u32 w[8];
  #pragma unroll
  for (int p = 0; p < 8; ++p){
    u16 lo = f2bf(T[c * 33 + mh + p * 2]);
    u16 hi = f2bf(T[c * 33 + mh + p * 2 + 1]);
    w[p] = (u32)lo | ((u32)hi << 16);
  }
  int b = R0 >> 11;
  size_t base = ((size_t)(b * 128 + c)) * 2048 + (R0 & 2047) + mh;
  *(uint4*)(zT + base)     = make_uint4(w[0], w[1], w[2], w[3]);
  *(uint4*)(zT + base + 8) = make_uint4(w[4], w[5], w[6], w[7]);
}

// ---------------- logits -> exp tables: E=exp(e), E01=exp(0.01e) ----------------
__global__ __launch_bounds__(256) void ke(const float* __restrict__ hA, const float* __restrict__ hB,
                                          const float* __restrict__ vA, const float* __restrict__ vB,
                                          const float* __restrict__ cA, const float* __restrict__ cB,
                                          float* __restrict__ EAe, float* __restrict__ EA01e,
                                          float* __restrict__ EBe, float* __restrict__ EB01e){
  __shared__ float h_l[32 * 132];
  __shared__ float v_l[8 * 132];
  __shared__ float c_l[8];
  int gid = blockIdx.x, t = threadIdx.x;
  int X = gid >> 8;
  int r0 = (gid & 255) * 32;
  const float* hp = X ? hB : hA;
  const float* vp = X ? vB : vA;
  const float* cp = X ? cB : cA;

  for (int j = 0; j < 4; ++j){
    int idx4 = t + 256 * j;
    int r = idx4 >> 5, k0 = (idx4 & 31) * 4;
    *(float4*)&h_l[r * 132 + k0] = *(const float4*)&hp[(size_t)(r0 + r) * 128 + k0];
  }
  { int hh = t >> 5, k0 = (t & 31) * 4;
    *(float4*)&v_l[hh * 132 + k0] = *(const float4*)&vp[hh * 128 + k0]; }
  if (t < 8) c_l[t] = cp[t];
  __syncthreads();

  int r = t >> 3, h = t & 7;
  float acc = c_l[h];
  #pragma unroll
  for (int k0 = 0; k0 < 128; k0 += 4){
    float4 hv = *(const float4*)&h_l[r * 132 + k0];
    float4 vv = *(const float4*)&v_l[h * 132 + k0];
    acc = fmaf(hv.x, vv.x, acc); acc = fmaf(hv.y, vv.y, acc);
    acc = fmaf(hv.z, vv.z, acc); acc = fmaf(hv.w, vv.w, acc);
  }
  int row = r0 + r;
  int b = row >> 11, n = row & 2047;
  size_t idx = (size_t)(b * 8 + h) * 2048 + n;
  float e0 = __expf(acc), e1 = __expf(0.01f * acc);
  if (X){ EBe[idx] = e0; EB01e[idx] = e1; }
  else  { EAe[idx] = e0; EA01e[idx] = e1; }
}

// ---------------- attention: MFMA flash, m-split x4 + LDS reduce, prefetch-2 ----------------
// block = (b, 32-row n-tile, head); its 4 waves take 512-m quarters.
// 2048 blocks = 8 blocks/CU = 8 waves/SIMD. Waves 1-3 dump acc/L to LDS;
// wave 0 reduces, normalizes, stores. Prefetch depth 2 (overruns stay in ws).
__global__ __launch_bounds__(256) void kattn(const u16* __restrict__ zT,
                                             const float* __restrict__ EAe, const float* __restrict__ EA01e,
                                             const float* __restrict__ EBe, const float* __restrict__ EB01e,
                                             const u32* __restrict__ Mb,
                                             float* __restrict__ cat){
  __shared__ float red[3][32][17];   // [source wave-1][local row][16 cols + L]
  int t = threadIdx.x;
  int w = t >> 6, lane = t & 63;     // w = m-quarter
  int gid = blockIdx.x;              // 2048
  int h  = gid & 7;
  int nt = (gid >> 3) & 63;
  int b  = gid >> 9;
  int n0 = nt * 32;
  int nl = lane & 15, q = lane >> 4, qs = q * 8;

  size_t ebase = (size_t)(b * 8 + h) * 2048;
  float ea0  = EAe  [ebase + n0 + nl];
  float ea0s = EA01e[ebase + n0 + nl];
  float ea1  = EAe  [ebase + n0 + 16 + nl];
  float ea1s = EA01e[ebase + n0 + 16 + nl];

  const float* EBp = EBe   + ebase + w * 512;
  const float* GBp = EB01e + ebase + w * 512;
  const u16*  zp  = zT + ((size_t)(b * 128 + h * 16 + nl)) * 2048 + w * 512;
  const u32*  mp0 = Mb + ((size_t)(b * 2048) + n0 + nl) * 64 + w * 16;
  const u32*  mp1 = mp0 + 16 * 64;

  f32x4 acc0 = {0.f,0.f,0.f,0.f}, acc1 = {0.f,0.f,0.f,0.f};
  f32x4 lcc0 = {0.f,0.f,0.f,0.f}, lcc1 = {0.f,0.f,0.f,0.f};
  const short8 ones = {0x3F80,0x3F80,0x3F80,0x3F80,0x3F80,0x3F80,0x3F80,0x3F80};

  float4 Ae0,Ae1,Ag0,Ag1, Be0,Be1,Bg0,Bg1;
  short8 Az, Bz; u32 Am0, Am1, Bm0, Bm1;
  #define LOADA(sp) do{ int m_ = (sp) * 32 + qs; \
    Ae0 = *(const float4*)(EBp + m_); Ae1 = *(const float4*)(EBp + m_ + 4); \
    Ag0 = *(const float4*)(GBp + m_); Ag1 = *(const float4*)(GBp + m_ + 4); \
    Az  = *(const short8*)(zp + m_); Am0 = mp0[sp]; Am1 = mp1[sp]; }while(0)
  #define LOADB(sp) do{ int m_ = (sp) * 32 + qs; \
    Be0 = *(const float4*)(EBp + m_); Be1 = *(const float4*)(EBp + m_ + 4); \
    Bg0 = *(const float4*)(GBp + m_); Bg1 = *(const float4*)(GBp + m_ + 4); \
    Bz  = *(const short8*)(zp + m_); Bm0 = mp0[sp]; Bm1 = mp1[sp]; }while(0)
  #define COMP(E0_,E1_,G0_,G1_,Z_,M0_,M1_) do{ \
    float eb[8] = {E0_.x,E0_.y,E0_.z,E0_.w,E1_.x,E1_.y,E1_.z,E1_.w}; \
    float gb[8] = {G0_.x,G0_.y,G0_.z,G0_.w,G1_.x,G1_.y,G1_.z,G1_.w}; \
    u32 mb0 = (M0_) >> qs, mb1 = (M1_) >> qs; \
    union { u32 u[4]; short8 v; } af0, af1; \
    _Pragma("unroll") \
    for (int p = 0; p < 4; ++p){ \
      int j0 = 2*p, j1 = 2*p + 1; \
      u32 k00 = (u32)(((int)(mb0 << (31 - j0))) >> 31); \
      u32 k01 = (u32)(((int)(mb0 << (31 - j1))) >> 31); \
      u32 k10 = (u32)(((int)(mb1 << (31 - j0))) >> 31); \
      u32 k11 = (u32)(((int)(mb1 << (31 - j1))) >> 31); \
      float s00 = fmaxf(ea0 * eb[j0], ea0s * gb[j0]); \
      float s01 = fmaxf(ea0 * eb[j1], ea0s * gb[j1]); \
      float s10 = fmaxf(ea1 * eb[j0], ea1s * gb[j0]); \
      float s11 = fmaxf(ea1 * eb[j1], ea1s * gb[j1]); \
      u32 a00 = __float_as_uint(s00) & k00; \
      u32 a01 = __float_as_uint(s01) & k01; \
      u32 a10 = __float_as_uint(s10) & k10; \
      u32 a11 = __float_as_uint(s11) & k11; \
      af0.u[p] = __builtin_amdgcn_perm(a01, a00, 0x07060302u); \
      af1.u[p] = __builtin_amdgcn_perm(a11, a10, 0x07060302u); \
    } \
    acc0 = __builtin_amdgcn_mfma_f32_16x16x32_bf16(af0.v, Z_, acc0, 0, 0, 0); \
    lcc0 = __builtin_amdgcn_mfma_f32_16x16x32_bf16(af0.v, ones, lcc0, 0, 0, 0); \
    acc1 = __builtin_amdgcn_mfma_f32_16x16x32_bf16(af1.v, Z_, acc1, 0, 0, 0); \
    lcc1 = __builtin_amdgcn_mfma_f32_16x16x32_bf16(af1.v, ones, lcc1, 0, 0, 0); }while(0)

  LOADA(0);
  LOADB(1);
  #pragma unroll 4
  for (int s = 0; s < 16; s += 2){
    COMP(Ae0,Ae1,Ag0,Ag1,Az,Am0,Am1);
    LOADA(s + 2);                        // <=2-step overrun stays inside ws
    COMP(Be0,Be1,Bg0,Bg1,Bz,Bm0,Bm1);
    LOADB(s + 3);
  }
  #undef LOADA
  #undef LOADB
  #undef COMP

  if (w > 0){
    #pragma unroll
    for (int r = 0; r < 4; ++r){
      int row = q * 4 + r;
      red[w - 1][row][nl]      = acc0[r];
      red[w - 1][row + 16][nl] = acc1[r];
    }
    if (nl == 0){
      #pragma unroll
      for (int r = 0; r < 4; ++r){
        red[w - 1][q * 4 + r][16]      = lcc0[r];
        red[w - 1][q * 4 + r + 16][16] = lcc1[r];
      }
    }
  }
  __syncthreads();
  if (w == 0){
    #pragma unroll
    for (int r = 0; r < 4; ++r){
      int row = q * 4 + r;
      float a0 = acc0[r] + red[0][row][nl]      + red[1][row][nl]      + red[2][row][nl];
      float a1 = acc1[r] + red[0][row + 16][nl] + red[1][row + 16][nl] + red[2][row + 16][nl];
      float L0 = lcc0[r] + red[0][row][16]      + red[1][row][16]      + red[2][row][16];
      float L1 = lcc1[r] + red[0][row + 16][16] + red[1][row + 16][16] + red[2][row + 16][16];
      float r0 = (L0 > 0.f) ? 1.f / L0 : 0.f;
      float r1 = (L1 > 0.f) ? 1.f / L1 : 0.f;
      cat[((size_t)(b * 2048) + n0 + row)      * 128 + h * 16 + nl] = a0 * r0;
      cat[((size_t)(b * 2048) + n0 + 16 + row) * 128 + h * 16 + nl] = a1 * r1;
    }
  }
}

// ---------------- output GEMM: out = cat @ WtO + Wb ----------------
__global__ __launch_bounds__(256) void kout(const float* __restrict__ cat,
                                            const float* __restrict__ WtO, const float* __restrict__ Wb,
                                            float* __restrict__ out){
  __shared__ float cat_l[32 * 132];
  __shared__ float Wt_l[64 * 128];
  int R0 = blockIdx.x * 32;
  int t = threadIdx.x;

  for (int jj = 0; jj < 4; ++jj){
    int idx4 = t + 256 * jj;
    int r = idx4 >> 5, c0 = (idx4 & 31) * 4;
    *(float4*)&cat_l[r * 132 + c0] = *(const float4*)&cat[((size_t)R0 + r) * 128 + c0];
  }

  int og = t & 15, rg = t >> 4;
  float acc[2][8];
  for (int i = 0; i < 2; ++i) for (int s = 0; s < 8; ++s) acc[i][s] = 0.f;

  for (int kc = 0; kc < 2; ++kc){
    __syncthreads();
    for (int j = 0; j < 8; ++j){
      int idx4 = t + 256 * j;
      int k = idx4 >> 5, o0 = (idx4 & 31) * 4;
      *(float4*)&Wt_l[k * 128 + o0] = *(const float4*)&WtO[(kc * 64 + k) * 128 + o0];
    }
    __syncthreads();
    for (int k = 0; k < 64; ++k){
      int kk = kc * 64 + k;
      float4 w0 = *(const float4*)&Wt_l[k * 128 + og * 8];
      float4 w1 = *(const float4*)&Wt_l[k * 128 + og * 8 + 4];
      float wv[8] = {w0.x, w0.y, w0.z, w0.w, w1.x, w1.y, w1.z, w1.w};
      #pragma unroll
      for (int i = 0; i < 2; ++i){
        float cv = cat_l[(rg * 2 + i) * 132 + kk];
        #pragma unroll
        for (int s = 0; s < 8; ++s) acc[i][s] = fmaf(cv, wv[s], acc[i][s]);
      }
    }
  }

  for (int i = 0; i < 2; ++i){
    int r = rg * 2 + i;
    float* op = out + (size_t)(R0 + r) * 128 + og * 8;
    *(float4*)(op)     = make_float4(acc[i][0]+Wb[og*8+0], acc[i][1]+Wb[og*8+1], acc[i][2]+Wb[og*8+2], acc[i][3]+Wb[og*8+3]);
    *(float4*)(op + 4) = make_float4(acc[i][4]+Wb[og*8+4], acc[i][5]+Wb[og*8+5], acc[i][6]+Wb[og*8+6], acc[i][7]+Wb[og*8+7]);
  }
}

extern "C" void kernel_launch(void* const* d_in, const int* in_sizes, int n_in,
                              void* d_out, int out_size, void* d_ws, size_t ws_size,
                              hipStream_t stream) {
  const float* hA  = (const float*)d_in[0];
  const float* hB  = (const float*)d_in[1];
  const void* maskv= d_in[2];
  const float* WAw = (const float*)d_in[3];
  const float* WAb = (const float*)d_in[4];
  const float* WBw = (const float*)d_in[5];
  const float* WBb = (const float*)d_in[6];
  const float* aAw = (const float*)d_in[7];
  const float* aAb = (const float*)d_in[8];
  const float* aBw = (const float*)d_in[9];
  const float* aBb = (const float*)d_in[10];
  const float* Ww  = (const float*)d_in[11];
  const float* Wb  = (const float*)d_in[12];

  float* ws   = (float*)d_ws;
  u16*  zT    = (u16*)ws;             // 1,048,576 u16 = 524,288 float slots
  float* EAe  = ws + 524288;          // 65,536
  float* EA01e= ws + 589824;          // 65,536
  float* EBe  = ws + 655360;          // 65,536
  float* EB01e= ws + 720896;          // 65,536
  float* WfB  = ws + 786432;          // 16,384
  float* WtO  = ws + 802816;          // 16,384
  float* vA   = ws + 819200;          // 1,024
  float* vB   = ws + 820224;          // 1,024
  float* cA   = ws + 821248;          // 8
  float* cB   = ws + 821256;          // 8
  int*  flags = (int*)(ws + 821264);  // 8
  u32*  Mb    = (u32*)(ws + 821272);  // 524,288
  float* cat  = ws + 1345560;         // 1,048,576 -> total 2,394,136 floats

  if (ws_size < 2394136ull * 4ull){
    kzero<<<4096, 256, 0, stream>>>((float*)d_out);
    return;
  }

  kdet <<<1, 256, 0, stream>>>((const u32*)maskv, flags);
  kfold<<<136, 256, 0, stream>>>(WAw, WAb, WBw, WBb, aAw, aAb, aBw, aBb, Ww,
                                 WfB, WtO, vA, vB, cA, cB);
  kmask<<<2048, 256, 0, stream>>>(maskv, flags, Mb);
  kproj<<<256, 256, 0, stream>>>(hB, WfB, WBb, zT);
  ke   <<<512, 256, 0, stream>>>(hA, hB, vA, vB, cA, cB, EAe, EA01e, EBe, EB01e);
  kattn<<<2048, 256, 0, stream>>>(zT, EAe, EA01e, EBe, EB01e, Mb, cat);
  kout <<<256, 256, 0, stream>>>(cat, WtO, Wb, (float*)d_out);
}

// Round 12
// 188.256 us; speedup vs baseline: 1.0640x; 1.0640x over previous
//
#include <hip/hip_runtime.h>

typedef unsigned short u16;
typedef unsigned int u32;
typedef unsigned char u8;

typedef __attribute__((ext_vector_type(8))) short short8;   // 8 bf16
typedef __attribute__((ext_vector_type(4))) float f32x4;

// B=4, NA=NB=2048, IN=128, H=8, DH=16, C=128, OUT=128
// Inputs fp32; mask 32-bit words (kdet-detected); OUTPUT fp32.
// zF = MFMA-B-fragment-major bf16 z: zF[((b*8+h)*64+mblk)*64+lane] 16B
//      = z[d=lane&15][m=mblk*32+(lane>>4)*8 .. +8]  -> coalesced 1KB/wave load.

__device__ __forceinline__ u16 f2bf(float f){
  u32 u = __float_as_uint(f);
  u += 0x7fff + ((u >> 16) & 1);   // RNE
  return (u16)(u >> 16);
}

__global__ __launch_bounds__(256) void kzero(float* __restrict__ out){
  out[blockIdx.x * 256 + threadIdx.x] = 0.f;
}

// ---------------- mask encoding detect ----------------
__global__ __launch_bounds__(256) void kdet(const u32* __restrict__ mw, int* __restrict__ flags){
  __shared__ int allw, allhw, allbyte;
  int t = threadIdx.x;
  if (t == 0){ allw = 1; allhw = 1; allbyte = 1; }
  __syncthreads();
  int aw = 1, ah = 1, ab = 1;
  #pragma unroll
  for (int j = 0; j < 4; ++j){
    u32 m = mw[t + 256 * j];
    if (!(m == 0u || m == 1u || m == 0x3F800000u)) aw = 0;
    u32 lo = m & 0xFFFFu, hi = m >> 16;
    if (!((lo == 0u || lo == 1u || lo == 0x3F80u) && (hi == 0u || hi == 1u || hi == 0x3F80u))) ah = 0;
    if (m & ~0x01010101u) ab = 0;
  }
  if (!aw) atomicAnd(&allw, 0);
  if (!ah) atomicAnd(&allhw, 0);
  if (!ab) atomicAnd(&allbyte, 0);
  __syncthreads();
  if (t == 0){
    int fm = 0;
    if (allw) fm = 0; else if (allbyte) fm = 1; else if (allhw) fm = 2;
    flags[0] = fm;
  }
}

// ---------------- mask -> packed bits ----------------
// Mb[(b*2048+n)*64 + w] bit j = mask element w*32+j of row n.
__global__ __launch_bounds__(256) void kmask(const void* __restrict__ maskv,
                                             const int* __restrict__ flags,
                                             u32* __restrict__ Mb){
  int Fm = flags[0];
  int t = threadIdx.x;
  if (Fm == 0){
    int lane = t & 63;
    int wid = blockIdx.x * 4 + (t >> 6);       // 8192 waves
    const u32* mw = (const u32*)maskv;
    size_t base = (size_t)wid * 2048;          // 32 iters x 64 words
    #pragma unroll 4
    for (int i = 0; i < 32; ++i){
      u32 v = mw[base + i * 64 + lane];
      unsigned long long bal = __ballot(v != 0u);
      if (lane < 2) Mb[(base + i * 64) / 32 + lane] = (u32)(bal >> (32 * lane));
    }
    return;
  }
  int oid = blockIdx.x * 256 + t;              // one packed word per thread
  u32 bits = 0;
  if (Fm == 1){
    const uint4* mp = (const uint4*)maskv + (size_t)oid * 2;
    #pragma unroll
    for (int k = 0; k < 2; ++k){
      uint4 v = mp[k];
      u32 w[4] = {v.x, v.y, v.z, v.w};
      #pragma unroll
      for (int q = 0; q < 4; ++q)
        #pragma unroll
        for (int bb = 0; bb < 4; ++bb)
          bits |= ((w[q] >> (8*bb)) & 255u ? 1u : 0u) << (k*16 + q*4 + bb);
    }
  } else {
    const uint4* mp = (const uint4*)maskv + (size_t)oid * 4;
    #pragma unroll
    for (int k = 0; k < 4; ++k){
      uint4 v = mp[k];
      u32 w[4] = {v.x, v.y, v.z, v.w};
      #pragma unroll
      for (int q = 0; q < 4; ++q){
        bits |= ((w[q] & 0xFFFFu) ? 1u : 0u) << (k*8 + q*2);
        bits |= ((w[q] >> 16)     ? 1u : 0u) << (k*8 + q*2 + 1);
      }
    }
  }
  Mb[oid] = bits;
}

// ---------------- fold weights ----------------
__global__ __launch_bounds__(256) void kfold(const float* __restrict__ WA, const float* __restrict__ WAb,
                                             const float* __restrict__ WB, const float* __restrict__ WBb,
                                             const float* __restrict__ aAw, const float* __restrict__ aAb,
                                             const float* __restrict__ aBw, const float* __restrict__ aBb,
                                             const float* __restrict__ W,
                                             float* __restrict__ WfB, float* __restrict__ WtO,
                                             float* __restrict__ vA, float* __restrict__ vB,
                                             float* __restrict__ cA, float* __restrict__ cB){
  int gid = blockIdx.x, t = threadIdx.x;
  if (gid < 64){
    int idx = gid * 256 + t;
    int k = idx >> 7, c = idx & 127;
    WfB[idx] = WB[(c >> 4) * 2048 + k * 16 + (c & 15)];
  } else if (gid < 128){
    int idx = (gid - 64) * 256 + t;
    int c = idx >> 7, o = idx & 127;
    WtO[idx] = W[o * 128 + c];
  } else {
    int h = gid - 128;
    if (t < 128){
      float s = 0.f;
      #pragma unroll
      for (int d = 0; d < 16; ++d) s += WA[h * 2048 + t * 16 + d] * aAw[h * 16 + d];
      vA[h * 128 + t] = s;
    } else {
      int i = t - 128;
      float s = 0.f;
      #pragma unroll
      for (int d = 0; d < 16; ++d) s += WB[h * 2048 + i * 16 + d] * aBw[h * 16 + d];
      vB[h * 128 + i] = s;
    }
    if (t == 0){
      float s = aAb[h];
      #pragma unroll
      for (int d = 0; d < 16; ++d) s += WAb[h * 16 + d] * aAw[h * 16 + d];
      cA[h] = s;
    }
    if (t == 255){
      float s = aBb[h];
      #pragma unroll
      for (int d = 0; d < 16; ++d) s += WBb[h * 16 + d] * aBw[h * 16 + d];
      cB[h] = s;
    }
  }
}

// ---------------- projection -> fragment-major bf16 zF ----------------
__global__ __launch_bounds__(256) void kproj(const float* __restrict__ hB,
                                             const float* __restrict__ WfB,
                                             const float* __restrict__ bB,
                                             uint4* __restrict__ zF){
  __shared__ float h_l[32 * 132];
  __shared__ float W_l[64 * 128];
  __shared__ float T[128 * 33];     // [channel c][local m]
  int R0 = blockIdx.x * 32;
  int t = threadIdx.x;

  for (int j = 0; j < 4; ++j){
    int idx4 = t + 256 * j;
    int r = idx4 >> 5, k0 = (idx4 & 31) * 4;
    *(float4*)&h_l[r * 132 + k0] = *(const float4*)&hB[(size_t)(R0 + r) * 128 + k0];
  }

  int cg = t & 15, rg = t >> 4;
  float acc[2][8];
  for (int i = 0; i < 2; ++i) for (int s = 0; s < 8; ++s) acc[i][s] = 0.f;

  for (int kc = 0; kc < 2; ++kc){
    __syncthreads();
    for (int j = 0; j < 8; ++j){
      int idx4 = t + 256 * j;
      int k = idx4 >> 5, c0 = (idx4 & 31) * 4;
      *(float4*)&W_l[k * 128 + c0] = *(const float4*)&WfB[(kc * 64 + k) * 128 + c0];
    }
    __syncthreads();
    for (int k = 0; k < 64; ++k){
      int kk = kc * 64 + k;
      float4 w0 = *(const float4*)&W_l[k * 128 + cg * 8];
      float4 w1 = *(const float4*)&W_l[k * 128 + cg * 8 + 4];
      float wv[8] = {w0.x, w0.y, w0.z, w0.w, w1.x, w1.y, w1.z, w1.w};
      #pragma unroll
      for (int i = 0; i < 2; ++i){
        float hv = h_l[(rg * 2 + i) * 132 + kk];
        #pragma unroll
        for (int s = 0; s < 8; ++s) acc[i][s] = fmaf(hv, wv[s], acc[i][s]);
      }
    }
  }

  for (int i = 0; i < 2; ++i)
    #pragma unroll
    for (int s = 0; s < 8; ++s)
      T[(cg * 8 + s) * 33 + rg * 2 + i] = acc[i][s] + bB[cg * 8 + s];
  __syncthreads();

  // fragment-major store: item = (h, lane); 16B = bf16 z[d=lane&15][mq..mq+8]
  int b = R0 >> 11;
  int mblk = (R0 & 2047) >> 5;
  for (int it = t; it < 512; it += 256){
    int h = it >> 6, lane = it & 63;
    int d = lane & 15, mq = (lane >> 4) * 8;
    const float* Tp = &T[(h * 16 + d) * 33 + mq];
    u32 wv[4];
    #pragma unroll
    for (int p = 0; p < 4; ++p){
      u16 lo = f2bf(Tp[p * 2]);
      u16 hi = f2bf(Tp[p * 2 + 1]);
      wv[p] = (u32)lo | ((u32)hi << 16);
    }
    zF[((size_t)((b * 8 + h) * 64) + mblk) * 64 + lane] = make_uint4(wv[0], wv[1], wv[2], wv[3]);
  }
}

// ---------------- logits -> exp tables: E=exp(e), E01=exp(0.01e) ----------------
__global__ __launch_bounds__(256) void ke(const float* __restrict__ hA, const float* __restrict__ hB,
                                          const float* __restrict__ vA, const float* __restrict__ vB,
                                          const float* __restrict__ cA, const float* __restrict__ cB,
                                          float* __restrict__ EAe, float* __restrict__ EA01e,
                                          float* __restrict__ EBe, float* __restrict__ EB01e){
  __shared__ float h_l[32 * 132];
  __shared__ float v_l[8 * 132];
  __shared__ float c_l[8];
  int gid = blockIdx.x, t = threadIdx.x;
  int X = gid >> 8;
  int r0 = (gid & 255) * 32;
  const float* hp = X ? hB : hA;
  const float* vp = X ? vB : vA;
  const float* cp = X ? cB : cA;

  for (int j = 0; j < 4; ++j){
    int idx4 = t + 256 * j;
    int r = idx4 >> 5, k0 = (idx4 & 31) * 4;
    *(float4*)&h_l[r * 132 + k0] = *(const float4*)&hp[(size_t)(r0 + r) * 128 + k0];
  }
  { int hh = t >> 5, k0 = (t & 31) * 4;
    *(float4*)&v_l[hh * 132 + k0] = *(const float4*)&vp[hh * 128 + k0]; }
  if (t < 8) c_l[t] = cp[t];
  __syncthreads();

  int r = t >> 3, h = t & 7;
  float acc = c_l[h];
  #pragma unroll
  for (int k0 = 0; k0 < 128; k0 += 4){
    float4 hv = *(const float4*)&h_l[r * 132 + k0];
    float4 vv = *(const float4*)&v_l[h * 132 + k0];
    acc = fmaf(hv.x, vv.x, acc); acc = fmaf(hv.y, vv.y, acc);
    acc = fmaf(hv.z, vv.z, acc); acc = fmaf(hv.w, vv.w, acc);
  }
  int row = r0 + r;
  int b = row >> 11, n = row & 2047;
  size_t idx = (size_t)(b * 8 + h) * 2048 + n;
  float e0 = __expf(acc), e1 = __expf(0.01f * acc);
  if (X){ EBe[idx] = e0; EB01e[idx] = e1; }
  else  { EAe[idx] = e0; EA01e[idx] = e1; }
}

// ---------------- attention: MFMA flash, m-split x4, coalesced zF ----------------
__global__ __launch_bounds__(256) void kattn(const uint4* __restrict__ zF,
                                             const float* __restrict__ EAe, const float* __restrict__ EA01e,
                                             const float* __restrict__ EBe, const float* __restrict__ EB01e,
                                             const u32* __restrict__ Mb,
                                             float* __restrict__ cat){
  __shared__ float red[3][32][17];   // [source wave-1][local row][16 cols + L]
  int t = threadIdx.x;
  int w = t >> 6, lane = t & 63;     // w = m-quarter
  int gid = blockIdx.x;              // 2048
  int h  = gid & 7;
  int nt = (gid >> 3) & 63;
  int b  = gid >> 9;
  int n0 = nt * 32;
  int nl = lane & 15, q = lane >> 4, qs = q * 8;

  size_t ebase = (size_t)(b * 8 + h) * 2048;
  float ea0  = EAe  [ebase + n0 + nl];
  float ea0s = EA01e[ebase + n0 + nl];
  float ea1  = EAe  [ebase + n0 + 16 + nl];
  float ea1s = EA01e[ebase + n0 + 16 + nl];

  const float* EBp = EBe   + ebase + w * 512;
  const float* GBp = EB01e + ebase + w * 512;
  const uint4* zFp = zF + ((size_t)(b * 8 + h) * 64 + w * 16) * 64 + lane;  // coalesced
  const u32*  mp0 = Mb + ((size_t)(b * 2048) + n0 + nl) * 64 + w * 16;
  const u32*  mp1 = mp0 + 16 * 64;

  f32x4 acc0 = {0.f,0.f,0.f,0.f}, acc1 = {0.f,0.f,0.f,0.f};
  f32x4 lcc0 = {0.f,0.f,0.f,0.f}, lcc1 = {0.f,0.f,0.f,0.f};
  const short8 ones = {0x3F80,0x3F80,0x3F80,0x3F80,0x3F80,0x3F80,0x3F80,0x3F80};

  float4 Ae0,Ae1,Ag0,Ag1, Be0,Be1,Bg0,Bg1;
  uint4 Azu, Bzu; u32 Am0, Am1, Bm0, Bm1;
  #define LOADA(sp) do{ int m_ = (sp) * 32 + qs; \
    Ae0 = *(const float4*)(EBp + m_); Ae1 = *(const float4*)(EBp + m_ + 4); \
    Ag0 = *(const float4*)(GBp + m_); Ag1 = *(const float4*)(GBp + m_ + 4); \
    Azu = zFp[(size_t)(sp) * 64]; Am0 = mp0[sp]; Am1 = mp1[sp]; }while(0)
  #define LOADB(sp) do{ int m_ = (sp) * 32 + qs; \
    Be0 = *(const float4*)(EBp + m_); Be1 = *(const float4*)(EBp + m_ + 4); \
    Bg0 = *(const float4*)(GBp + m_); Bg1 = *(const float4*)(GBp + m_ + 4); \
    Bzu = zFp[(size_t)(sp) * 64]; Bm0 = mp0[sp]; Bm1 = mp1[sp]; }while(0)
  #define COMP(E0_,E1_,G0_,G1_,ZU_,M0_,M1_) do{ \
    float eb[8] = {E0_.x,E0_.y,E0_.z,E0_.w,E1_.x,E1_.y,E1_.z,E1_.w}; \
    float gb[8] = {G0_.x,G0_.y,G0_.z,G0_.w,G1_.x,G1_.y,G1_.z,G1_.w}; \
    union { uint4 u; short8 v; } zu; zu.u = ZU_; \
    u32 mb0 = (M0_) >> qs, mb1 = (M1_) >> qs; \
    union { u32 u[4]; short8 v; } af0, af1; \
    _Pragma("unroll") \
    for (int p = 0; p < 4; ++p){ \
      int j0 = 2*p, j1 = 2*p + 1; \
      u32 k00 = (u32)(((int)(mb0 << (31 - j0))) >> 31); \
      u32 k01 = (u32)(((int)(mb0 << (31 - j1))) >> 31); \
      u32 k10 = (u32)(((int)(mb1 << (31 - j0))) >> 31); \
      u32 k11 = (u32)(((int)(mb1 << (31 - j1))) >> 31); \
      float s00 = fmaxf(ea0 * eb[j0], ea0s * gb[j0]); \
      float s01 = fmaxf(ea0 * eb[j1], ea0s * gb[j1]); \
      float s10 = fmaxf(ea1 * eb[j0], ea1s * gb[j0]); \
      float s11 = fmaxf(ea1 * eb[j1], ea1s * gb[j1]); \
      u32 a00 = __float_as_uint(s00) & k00; \
      u32 a01 = __float_as_uint(s01) & k01; \
      u32 a10 = __float_as_uint(s10) & k10; \
      u32 a11 = __float_as_uint(s11) & k11; \
      af0.u[p] = __builtin_amdgcn_perm(a01, a00, 0x07060302u); \
      af1.u[p] = __builtin_amdgcn_perm(a11, a10, 0x07060302u); \
    } \
    acc0 = __builtin_amdgcn_mfma_f32_16x16x32_bf16(af0.v, zu.v, acc0, 0, 0, 0); \
    lcc0 = __builtin_amdgcn_mfma_f32_16x16x32_bf16(af0.v, ones, lcc0, 0, 0, 0); \
    acc1 = __builtin_amdgcn_mfma_f32_16x16x32_bf16(af1.v, zu.v, acc1, 0, 0, 0); \
    lcc1 = __builtin_amdgcn_mfma_f32_16x16x32_bf16(af1.v, ones, lcc1, 0, 0, 0); }while(0)

  LOADA(0);
  LOADB(1);
  #pragma unroll 4
  for (int s = 0; s < 16; s += 2){
    COMP(Ae0,Ae1,Ag0,Ag1,Azu,Am0,Am1);
    LOADA(s + 2);                        // <=2-step overrun stays inside ws
    COMP(Be0,Be1,Bg0,Bg1,Bzu,Bm0,Bm1);
    LOADB(s + 3);
  }
  #undef LOADA
  #undef LOADB
  #undef COMP

  if (w > 0){
    #pragma unroll
    for (int r = 0; r < 4; ++r){
      int row = q * 4 + r;
      red[w - 1][row][nl]      = acc0[r];
      red[w - 1][row + 16][nl] = acc1[r];
    }
    if (nl == 0){
      #pragma unroll
      for (int r = 0; r < 4; ++r){
        red[w - 1][q * 4 + r][16]      = lcc0[r];
        red[w - 1][q * 4 + r + 16][16] = lcc1[r];
      }
    }
  }
  __syncthreads();
  if (w == 0){
    #pragma unroll
    for (int r = 0; r < 4; ++r){
      int row = q * 4 + r;
      float a0 = acc0[r] + red[0][row][nl]      + red[1][row][nl]      + red[2][row][nl];
      float a1 = acc1[r] + red[0][row + 16][nl] + red[1][row + 16][nl] + red[2][row + 16][nl];
      float L0 = lcc0[r] + red[0][row][16]      + red[1][row][16]      + red[2][row][16];
      float L1 = lcc1[r] + red[0][row + 16][16] + red[1][row + 16][16] + red[2][row + 16][16];
      float r0 = (L0 > 0.f) ? 1.f / L0 : 0.f;
      float r1 = (L1 > 0.f) ? 1.f / L1 : 0.f;
      cat[((size_t)(b * 2048) + n0 + row)      * 128 + h * 16 + nl] = a0 * r0;
      cat[((size_t)(b * 2048) + n0 + 16 + row) * 128 + h * 16 + nl] = a1 * r1;
    }
  }
}

// ---------------- output GEMM: out = cat @ WtO + Wb ----------------
__global__ __launch_bounds__(256) void kout(const float* __restrict__ cat,
                                            const float* __restrict__ WtO, const float* __restrict__ Wb,
                                            float* __restrict__ out){
  __shared__ float cat_l[32 * 132];
  __shared__ float Wt_l[64 * 128];
  int R0 = blockIdx.x * 32;
  int t = threadIdx.x;

  for (int jj = 0; jj < 4; ++jj){
    int idx4 = t + 256 * jj;
    int r = idx4 >> 5, c0 = (idx4 & 31) * 4;
    *(float4*)&cat_l[r * 132 + c0] = *(const float4*)&cat[((size_t)R0 + r) * 128 + c0];
  }

  int og = t & 15, rg = t >> 4;
  float acc[2][8];
  for (int i = 0; i < 2; ++i) for (int s = 0; s < 8; ++s) acc[i][s] = 0.f;

  for (int kc = 0; kc < 2; ++kc){
    __syncthreads();
    for (int j = 0; j < 8; ++j){
      int idx4 = t + 256 * j;
      int k = idx4 >> 5, o0 = (idx4 & 31) * 4;
      *(float4*)&Wt_l[k * 128 + o0] = *(const float4*)&WtO[(kc * 64 + k) * 128 + o0];
    }
    __syncthreads();
    for (int k = 0; k < 64; ++k){
      int kk = kc * 64 + k;
      float4 w0 = *(const float4*)&Wt_l[k * 128 + og * 8];
      float4 w1 = *(const float4*)&Wt_l[k * 128 + og * 8 + 4];
      float wv[8] = {w0.x, w0.y, w0.z, w0.w, w1.x, w1.y, w1.z, w1.w};
      #pragma unroll
      for (int i = 0; i < 2; ++i){
        float cv = cat_l[(rg * 2 + i) * 132 + kk];
        #pragma unroll
        for (int s = 0; s < 8; ++s) acc[i][s] = fmaf(cv, wv[s], acc[i][s]);
      }
    }
  }

  for (int i = 0; i < 2; ++i){
    int r = rg * 2 + i;
    float* op = out + (size_t)(R0 + r) * 128 + og * 8;
    *(float4*)(op)     = make_float4(acc[i][0]+Wb[og*8+0], acc[i][1]+Wb[og*8+1], acc[i][2]+Wb[og*8+2], acc[i][3]+Wb[og*8+3]);
    *(float4*)(op + 4) = make_float4(acc[i][4]+Wb[og*8+4], acc[i][5]+Wb[og*8+5], acc[i][6]+Wb[og*8+6], acc[i][7]+Wb[og*8+7]);
  }
}

extern "C" void kernel_launch(void* const* d_in, const int* in_sizes, int n_in,
                              void* d_out, int out_size, void* d_ws, size_t ws_size,
                              hipStream_t stream) {
  const float* hA  = (const float*)d_in[0];
  const float* hB  = (const float*)d_in[1];
  const void* maskv= d_in[2];
  const float* WAw = (const float*)d_in[3];
  const float* WAb = (const float*)d_in[4];
  const float* WBw = (const float*)d_in[5];
  const float* WBb = (const float*)d_in[6];
  const float* aAw = (const float*)d_in[7];
  const float* aAb = (const float*)d_in[8];
  const float* aBw = (const float*)d_in[9];
  const float* aBb = (const float*)d_in[10];
  const float* Ww  = (const float*)d_in[11];
  const float* Wb  = (const float*)d_in[12];

  float* ws   = (float*)d_ws;
  uint4* zF   = (uint4*)ws;           // 131,072 uint4 = 524,288 float slots
  float* EAe  = ws + 524288;          // 65,536
  float* EA01e= ws + 589824;          // 65,536
  float* EBe  = ws + 655360;          // 65,536
  float* EB01e= ws + 720896;          // 65,536
  float* WfB  = ws + 786432;          // 16,384
  float* WtO  = ws + 802816;          // 16,384
  float* vA   = ws + 819200;          // 1,024
  float* vB   = ws + 820224;          // 1,024
  float* cA   = ws + 821248;          // 8
  float* cB   = ws + 821256;          // 8
  int*  flags = (int*)(ws + 821264);  // 8
  u32*  Mb    = (u32*)(ws + 821272);  // 524,288
  float* cat  = ws + 1345560;         // 1,048,576 -> total 2,394,136 floats

  if (ws_size < 2394136ull * 4ull){
    kzero<<<4096, 256, 0, stream>>>((float*)d_out);
    return;
  }

  kdet <<<1, 256, 0, stream>>>((const u32*)maskv, flags);
  kfold<<<136, 256, 0, stream>>>(WAw, WAb, WBw, WBb, aAw, aAb, aBw, aBb, Ww,
                                 WfB, WtO, vA, vB, cA, cB);
  kmask<<<2048, 256, 0, stream>>>(maskv, flags, Mb);
  kproj<<<256, 256, 0, stream>>>(hB, WfB, WBb, zF);
  ke   <<<512, 256, 0, stream>>>(hA, hB, vA, vB, cA, cB, EAe, EA01e, EBe, EB01e);
  kattn<<<2048, 256, 0, stream>>>(zF, EAe, EA01e, EBe, EB01e, Mb, cat);
  kout <<<256, 256, 0, stream>>>(cat, WtO, Wb, (float*)d_out);
}

// Round 14
// 182.413 us; speedup vs baseline: 1.0981x; 1.0320x over previous
//
#include <hip/hip_runtime.h>

typedef unsigned short u16;
typedef unsigned int u32;
typedef unsigned char u8;

typedef _Float16 f16x8 __attribute__((ext_vector_type(8)));   // 8 f16 (4 VGPRs)
typedef _Float16 f16x2 __attribute__((ext_vector_type(2)));   // packed pair
typedef __attribute__((ext_vector_type(4))) float f32x4;

// B=4, NA=NB=2048, IN=128, H=8, DH=16, C=128, OUT=128
// Inputs fp32; mask 32-bit words (self-detected per kmask block); OUTPUT fp32.
// S-path in f16: EBh/GBh packed f16 pair tables, zF f16 fragment-major,
// MFMA f32_16x16x32_f16. Masked S dword == A-frag dword (no repack).
// NOTE: uses _Float16 vectors + __builtin_elementwise_max (v_pk_mul_f16 /
// v_pk_max_f16) -- ROCm 7.2 lacks __hmax2 (R13 compile failure).

__global__ __launch_bounds__(256) void kzero(float* __restrict__ out){
  out[blockIdx.x * 256 + threadIdx.x] = 0.f;
}

// ---------------- mask -> packed bits, encoding self-detected ----------------
// Mb[(b*2048+n)*64 + w] bit j = mask element w*32+j of row n.
__global__ __launch_bounds__(256) void kmask(const void* __restrict__ maskv,
                                             u32* __restrict__ Mb){
  __shared__ int s_aw, s_ab, s_ah;
  int t = threadIdx.x;
  if (t == 0){ s_aw = 1; s_ab = 1; s_ah = 1; }
  __syncthreads();
  {
    const u32* mw = (const u32*)maskv;   // same first 1024 words in every block
    int aw = 1, ah = 1, ab = 1;
    #pragma unroll
    for (int j = 0; j < 4; ++j){
      u32 m = mw[t + 256 * j];
      if (!(m == 0u || m == 1u || m == 0x3F800000u)) aw = 0;
      u32 lo = m & 0xFFFFu, hi = m >> 16;
      if (!((lo == 0u || lo == 1u || lo == 0x3F80u) && (hi == 0u || hi == 1u || hi == 0x3F80u))) ah = 0;
      if (m & ~0x01010101u) ab = 0;
    }
    if (!aw) atomicAnd(&s_aw, 0);
    if (!ah) atomicAnd(&s_ah, 0);
    if (!ab) atomicAnd(&s_ab, 0);
  }
  __syncthreads();
  int Fm = 0;
  if (s_aw) Fm = 0; else if (s_ab) Fm = 1; else if (s_ah) Fm = 2;

  if (Fm == 0){
    int lane = t & 63;
    int wid = blockIdx.x * 4 + (t >> 6);       // 8192 waves
    const u32* mw = (const u32*)maskv;
    size_t base = (size_t)wid * 2048;          // 32 iters x 64 words
    #pragma unroll 4
    for (int i = 0; i < 32; ++i){
      u32 v = mw[base + i * 64 + lane];
      unsigned long long bal = __ballot(v != 0u);
      if (lane < 2) Mb[(base + i * 64) / 32 + lane] = (u32)(bal >> (32 * lane));
    }
    return;
  }
  int oid = blockIdx.x * 256 + t;              // one packed word per thread
  u32 bits = 0;
  if (Fm == 1){
    const uint4* mp = (const uint4*)maskv + (size_t)oid * 2;
    #pragma unroll
    for (int k = 0; k < 2; ++k){
      uint4 v = mp[k];
      u32 w[4] = {v.x, v.y, v.z, v.w};
      #pragma unroll
      for (int q = 0; q < 4; ++q)
        #pragma unroll
        for (int bb = 0; bb < 4; ++bb)
          bits |= ((w[q] >> (8*bb)) & 255u ? 1u : 0u) << (k*16 + q*4 + bb);
    }
  } else {
    const uint4* mp = (const uint4*)maskv + (size_t)oid * 4;
    #pragma unroll
    for (int k = 0; k < 4; ++k){
      uint4 v = mp[k];
      u32 w[4] = {v.x, v.y, v.z, v.w};
      #pragma unroll
      for (int q = 0; q < 4; ++q){
        bits |= ((w[q] & 0xFFFFu) ? 1u : 0u) << (k*8 + q*2);
        bits |= ((w[q] >> 16)     ? 1u : 0u) << (k*8 + q*2 + 1);
      }
    }
  }
  Mb[oid] = bits;
}

// ---------------- fold weights ----------------
__global__ __launch_bounds__(256) void kfold(const float* __restrict__ WA, const float* __restrict__ WAb,
                                             const float* __restrict__ WB, const float* __restrict__ WBb,
                                             const float* __restrict__ aAw, const float* __restrict__ aAb,
                                             const float* __restrict__ aBw, const float* __restrict__ aBb,
                                             const float* __restrict__ W,
                                             float* __restrict__ WfB, float* __restrict__ WtO,
                                             float* __restrict__ vA, float* __restrict__ vB,
                                             float* __restrict__ cA, float* __restrict__ cB){
  int gid = blockIdx.x, t = threadIdx.x;
  if (gid < 64){
    int idx = gid * 256 + t;
    int k = idx >> 7, c = idx & 127;
    WfB[idx] = WB[(c >> 4) * 2048 + k * 16 + (c & 15)];
  } else if (gid < 128){
    int idx = (gid - 64) * 256 + t;
    int c = idx >> 7, o = idx & 127;
    WtO[idx] = W[o * 128 + c];
  } else {
    int h = gid - 128;
    if (t < 128){
      float s = 0.f;
      #pragma unroll
      for (int d = 0; d < 16; ++d) s += WA[h * 2048 + t * 16 + d] * aAw[h * 16 + d];
      vA[h * 128 + t] = s;
    } else {
      int i = t - 128;
      float s = 0.f;
      #pragma unroll
      for (int d = 0; d < 16; ++d) s += WB[h * 2048 + i * 16 + d] * aBw[h * 16 + d];
      vB[h * 128 + i] = s;
    }
    if (t == 0){
      float s = aAb[h];
      #pragma unroll
      for (int d = 0; d < 16; ++d) s += WAb[h * 16 + d] * aAw[h * 16 + d];
      cA[h] = s;
    }
    if (t == 255){
      float s = aBb[h];
      #pragma unroll
      for (int d = 0; d < 16; ++d) s += WBb[h * 16 + d] * aBw[h * 16 + d];
      cB[h] = s;
    }
  }
}

// ---------------- projection -> fragment-major f16 zF ----------------
__global__ __launch_bounds__(256) void kproj(const float* __restrict__ hB,
                                             const float* __restrict__ WfB,
                                             const float* __restrict__ bB,
                                             uint4* __restrict__ zF){
  __shared__ float h_l[32 * 132];
  __shared__ float W_l[64 * 128];
  __shared__ float T[128 * 33];     // [channel c][local m]
  int R0 = blockIdx.x * 32;
  int t = threadIdx.x;

  for (int j = 0; j < 4; ++j){
    int idx4 = t + 256 * j;
    int r = idx4 >> 5, k0 = (idx4 & 31) * 4;
    *(float4*)&h_l[r * 132 + k0] = *(const float4*)&hB[(size_t)(R0 + r) * 128 + k0];
  }

  int cg = t & 15, rg = t >> 4;
  float acc[2][8];
  for (int i = 0; i < 2; ++i) for (int s = 0; s < 8; ++s) acc[i][s] = 0.f;

  for (int kc = 0; kc < 2; ++kc){
    __syncthreads();
    for (int j = 0; j < 8; ++j){
      int idx4 = t + 256 * j;
      int k = idx4 >> 5, c0 = (idx4 & 31) * 4;
      *(float4*)&W_l[k * 128 + c0] = *(const float4*)&WfB[(kc * 64 + k) * 128 + c0];
    }
    __syncthreads();
    for (int k = 0; k < 64; ++k){
      int kk = kc * 64 + k;
      float4 w0 = *(const float4*)&W_l[k * 128 + cg * 8];
      float4 w1 = *(const float4*)&W_l[k * 128 + cg * 8 + 4];
      float wv[8] = {w0.x, w0.y, w0.z, w0.w, w1.x, w1.y, w1.z, w1.w};
      #pragma unroll
      for (int i = 0; i < 2; ++i){
        float hv = h_l[(rg * 2 + i) * 132 + kk];
        #pragma unroll
        for (int s = 0; s < 8; ++s) acc[i][s] = fmaf(hv, wv[s], acc[i][s]);
      }
    }
  }

  for (int i = 0; i < 2; ++i)
    #pragma unroll
    for (int s = 0; s < 8; ++s)
      T[(cg * 8 + s) * 33 + rg * 2 + i] = acc[i][s] + bB[cg * 8 + s];
  __syncthreads();

  // fragment-major store: item = (h, lane); 16B = f16 z[d=lane&15][mq..mq+8]
  int b = R0 >> 11;
  int mblk = (R0 & 2047) >> 5;
  for (int it = t; it < 512; it += 256){
    int h = it >> 6, lane = it & 63;
    int d = lane & 15, mq = (lane >> 4) * 8;
    const float* Tp = &T[(h * 16 + d) * 33 + mq];
    u32 wv[4];
    #pragma unroll
    for (int p = 0; p < 4; ++p){
      union { f16x2 h2; u32 u; } c;
      c.h2 = (f16x2){(_Float16)Tp[p * 2], (_Float16)Tp[p * 2 + 1]};
      wv[p] = c.u;
    }
    zF[((size_t)((b * 8 + h) * 64) + mblk) * 64 + lane] = make_uint4(wv[0], wv[1], wv[2], wv[3]);
  }
}

// ---------------- logits -> exp tables ----------------
// A side: fp32 EAe/EA01e. B side: packed f16 pair tables EBh/GBh.
__global__ __launch_bounds__(256) void ke(const float* __restrict__ hA, const float* __restrict__ hB,
                                          const float* __restrict__ vA, const float* __restrict__ vB,
                                          const float* __restrict__ cA, const float* __restrict__ cB,
                                          float* __restrict__ EAe, float* __restrict__ EA01e,
                                          u32* __restrict__ EBh, u32* __restrict__ GBh){
  __shared__ float h_l[32 * 132];
  __shared__ float v_l[8 * 132];
  __shared__ float c_l[8];
  int gid = blockIdx.x, t = threadIdx.x;
  int X = gid >> 8;
  int r0 = (gid & 255) * 32;
  const float* hp = X ? hB : hA;
  const float* vp = X ? vB : vA;
  const float* cp = X ? cB : cA;

  for (int j = 0; j < 4; ++j){
    int idx4 = t + 256 * j;
    int r = idx4 >> 5, k0 = (idx4 & 31) * 4;
    *(float4*)&h_l[r * 132 + k0] = *(const float4*)&hp[(size_t)(r0 + r) * 128 + k0];
  }
  { int hh = t >> 5, k0 = (t & 31) * 4;
    *(float4*)&v_l[hh * 132 + k0] = *(const float4*)&vp[hh * 128 + k0]; }
  if (t < 8) c_l[t] = cp[t];
  __syncthreads();

  int r = t >> 3, h = t & 7;
  float acc = c_l[h];
  #pragma unroll
  for (int k0 = 0; k0 < 128; k0 += 4){
    float4 hv = *(const float4*)&h_l[r * 132 + k0];
    float4 vv = *(const float4*)&v_l[h * 132 + k0];
    acc = fmaf(hv.x, vv.x, acc); acc = fmaf(hv.y, vv.y, acc);
    acc = fmaf(hv.z, vv.z, acc); acc = fmaf(hv.w, vv.w, acc);
  }
  int row = r0 + r;
  int b = row >> 11, n = row & 2047;
  float e0 = __expf(acc), e1 = __expf(0.01f * acc);
  if (X){
    // pair partner (n xor 1) lives at lane xor 8 (r parity = lane bit 3)
    float p0 = __shfl_xor(e0, 8, 64);
    float p1 = __shfl_xor(e1, 8, 64);
    if ((((t & 63) >> 3) & 1) == 0){
      union { f16x2 h2; u32 u; } c0, c1;
      c0.h2 = (f16x2){(_Float16)e0, (_Float16)p0};
      c1.h2 = (f16x2){(_Float16)e1, (_Float16)p1};
      u32 di = (u32)((b * 8 + h) * 1024 + (n >> 1));
      EBh[di] = c0.u;
      GBh[di] = c1.u;
    }
  } else {
    size_t idx = (size_t)(b * 8 + h) * 2048 + n;
    EAe[idx] = e0; EA01e[idx] = e1;
  }
}

// ---------------- attention: f16 MFMA flash, m-split x4, packed-f16 S-gen ----------------
__global__ __launch_bounds__(256) void kattn(const uint4* __restrict__ zF,
                                             const float* __restrict__ EAe, const float* __restrict__ EA01e,
                                             const u32* __restrict__ EBh, const u32* __restrict__ GBh,
                                             const u32* __restrict__ Mb,
                                             float* __restrict__ cat){
  __shared__ float red[3][32][17];   // [source wave-1][local row][16 cols + L]
  int t = threadIdx.x;
  int w = t >> 6, lane = t & 63;     // w = m-quarter
  int gid = blockIdx.x;              // 2048
  int h  = gid & 7;
  int nt = (gid >> 3) & 63;
  int b  = gid >> 9;
  int n0 = nt * 32;
  int nl = lane & 15, q = lane >> 4, qs = q * 8;

  size_t ebase = (size_t)(b * 8 + h) * 2048;
  _Float16 ea0h  = (_Float16)EAe  [ebase + n0 + nl];
  _Float16 ea0sh = (_Float16)EA01e[ebase + n0 + nl];
  _Float16 ea1h  = (_Float16)EAe  [ebase + n0 + 16 + nl];
  _Float16 ea1sh = (_Float16)EA01e[ebase + n0 + 16 + nl];
  f16x2 ea0_2  = (f16x2){ea0h,  ea0h};
  f16x2 ea0s_2 = (f16x2){ea0sh, ea0sh};
  f16x2 ea1_2  = (f16x2){ea1h,  ea1h};
  f16x2 ea1s_2 = (f16x2){ea1sh, ea1sh};

  const u32*  EBp = EBh + (size_t)(b * 8 + h) * 1024 + w * 256;   // dword = m-pair
  const u32*  GBp = GBh + (size_t)(b * 8 + h) * 1024 + w * 256;
  const uint4* zFp = zF + ((size_t)(b * 8 + h) * 64 + w * 16) * 64 + lane;  // coalesced
  const u32*  mp0 = Mb + ((size_t)(b * 2048) + n0 + nl) * 64 + w * 16;
  const u32*  mp1 = mp0 + 16 * 64;

  f32x4 acc0 = {0.f,0.f,0.f,0.f}, acc1 = {0.f,0.f,0.f,0.f};
  f32x4 lcc0 = {0.f,0.f,0.f,0.f}, lcc1 = {0.f,0.f,0.f,0.f};
  union { u32 u[4]; f16x8 v; } onesu;
  onesu.u[0] = 0x3C003C00u; onesu.u[1] = 0x3C003C00u;
  onesu.u[2] = 0x3C003C00u; onesu.u[3] = 0x3C003C00u;
  const f16x8 ones = onesu.v;

  uint4 Aeb, Agb, Azu, Beb, Bgb, Bzu; u32 Am0, Am1, Bm0, Bm1;
  #define LOADA(sp) do{ int d_ = (sp) * 16 + q * 4; \
    Aeb = *(const uint4*)(EBp + d_); Agb = *(const uint4*)(GBp + d_); \
    Azu = zFp[(size_t)(sp) * 64]; Am0 = mp0[sp]; Am1 = mp1[sp]; }while(0)
  #define LOADB(sp) do{ int d_ = (sp) * 16 + q * 4; \
    Beb = *(const uint4*)(EBp + d_); Bgb = *(const uint4*)(GBp + d_); \
    Bzu = zFp[(size_t)(sp) * 64]; Bm0 = mp0[sp]; Bm1 = mp1[sp]; }while(0)
  #define COMP(EB_,GB_,ZU_,M0_,M1_) do{ \
    u32 mb0 = (M0_) >> qs, mb1 = (M1_) >> qs; \
    u32 ebu[4] = {EB_.x, EB_.y, EB_.z, EB_.w}; \
    u32 gbu[4] = {GB_.x, GB_.y, GB_.z, GB_.w}; \
    union { u32 u[4]; f16x8 v; } a0, a1; \
    _Pragma("unroll") \
    for (int p = 0; p < 4; ++p){ \
      int j0 = 2*p, j1 = 2*p + 1; \
      u32 k00 = (u32)(((int)(mb0 << (31 - j0))) >> 31); \
      u32 k01 = (u32)(((int)(mb0 << (31 - j1))) >> 31); \
      u32 k10 = (u32)(((int)(mb1 << (31 - j0))) >> 31); \
      u32 k11 = (u32)(((int)(mb1 << (31 - j1))) >> 31); \
      u32 kc0 = __builtin_amdgcn_perm(k01, k00, 0x05040100u); \
      u32 kc1 = __builtin_amdgcn_perm(k11, k10, 0x05040100u); \
      union { u32 u; f16x2 h2; } eb, gb, r0u, r1u; \
      eb.u = ebu[p]; gb.u = gbu[p]; \
      r0u.h2 = __builtin_elementwise_max(ea0_2 * eb.h2, ea0s_2 * gb.h2); \
      r1u.h2 = __builtin_elementwise_max(ea1_2 * eb.h2, ea1s_2 * gb.h2); \
      a0.u[p] = r0u.u & kc0; \
      a1.u[p] = r1u.u & kc1; \
    } \
    union { uint4 u; f16x8 v; } zu; zu.u = ZU_; \
    acc0 = __builtin_amdgcn_mfma_f32_16x16x32_f16(a0.v, zu.v, acc0, 0, 0, 0); \
    lcc0 = __builtin_amdgcn_mfma_f32_16x16x32_f16(a0.v, ones, lcc0, 0, 0, 0); \
    acc1 = __builtin_amdgcn_mfma_f32_16x16x32_f16(a1.v, zu.v, acc1, 0, 0, 0); \
    lcc1 = __builtin_amdgcn_mfma_f32_16x16x32_f16(a1.v, ones, lcc1, 0, 0, 0); }while(0)

  LOADA(0);
  LOADB(1);
  #pragma unroll 4
  for (int s = 0; s < 16; s += 2){
    COMP(Aeb,Agb,Azu,Am0,Am1);
    LOADA(s + 2);                        // <=2-step overrun stays inside ws
    COMP(Beb,Bgb,Bzu,Bm0,Bm1);
    LOADB(s + 3);
  }
  #undef LOADA
  #undef LOADB
  #undef COMP

  if (w > 0){
    #pragma unroll
    for (int r = 0; r < 4; ++r){
      int row = q * 4 + r;
      red[w - 1][row][nl]      = acc0[r];
      red[w - 1][row + 16][nl] = acc1[r];
    }
    if (nl == 0){
      #pragma unroll
      for (int r = 0; r < 4; ++r){
        red[w - 1][q * 4 + r][16]      = lcc0[r];
        red[w - 1][q * 4 + r + 16][16] = lcc1[r];
      }
    }
  }
  __syncthreads();
  if (w == 0){
    #pragma unroll
    for (int r = 0; r < 4; ++r){
      int row = q * 4 + r;
      float a0 = acc0[r] + red[0][row][nl]      + red[1][row][nl]      + red[2][row][nl];
      float a1 = acc1[r] + red[0][row + 16][nl] + red[1][row + 16][nl] + red[2][row + 16][nl];
      float L0 = lcc0[r] + red[0][row][16]      + red[1][row][16]      + red[2][row][16];
      float L1 = lcc1[r] + red[0][row + 16][16] + red[1][row + 16][16] + red[2][row + 16][16];
      float r0 = (L0 > 0.f) ? 1.f / L0 : 0.f;
      float r1 = (L1 > 0.f) ? 1.f / L1 : 0.f;
      cat[((size_t)(b * 2048) + n0 + row)      * 128 + h * 16 + nl] = a0 * r0;
      cat[((size_t)(b * 2048) + n0 + 16 + row) * 128 + h * 16 + nl] = a1 * r1;
    }
  }
}

// ---------------- output GEMM: out = cat @ WtO + Wb ----------------
__global__ __launch_bounds__(256) void kout(const float* __restrict__ cat,
                                            const float* __restrict__ WtO, const float* __restrict__ Wb,
                                            float* __restrict__ out){
  __shared__ float cat_l[32 * 132];
  __shared__ float Wt_l[64 * 128];
  int R0 = blockIdx.x * 32;
  int t = threadIdx.x;

  for (int jj = 0; jj < 4; ++jj){
    int idx4 = t + 256 * jj;
    int r = idx4 >> 5, c0 = (idx4 & 31) * 4;
    *(float4*)&cat_l[r * 132 + c0] = *(const float4*)&cat[((size_t)R0 + r) * 128 + c0];
  }

  int og = t & 15, rg = t >> 4;
  float acc[2][8];
  for (int i = 0; i < 2; ++i) for (int s = 0; s < 8; ++s) acc[i][s] = 0.f;

  for (int kc = 0; kc < 2; ++kc){
    __syncthreads();
    for (int j = 0; j < 8; ++j){
      int idx4 = t + 256 * j;
      int k = idx4 >> 5, o0 = (idx4 & 31) * 4;
      *(float4*)&Wt_l[k * 128 + o0] = *(const float4*)&WtO[(kc * 64 + k) * 128 + o0];
    }
    __syncthreads();
    for (int k = 0; k < 64; ++k){
      int kk = kc * 64 + k;
      float4 w0 = *(const float4*)&Wt_l[k * 128 + og * 8];
      float4 w1 = *(const float4*)&Wt_l[k * 128 + og * 8 + 4];
      float wv[8] = {w0.x, w0.y, w0.z, w0.w, w1.x, w1.y, w1.z, w1.w};
      #pragma unroll
      for (int i = 0; i < 2; ++i){
        float cv = cat_l[(rg * 2 + i) * 132 + kk];
        #pragma unroll
        for (int s = 0; s < 8; ++s) acc[i][s] = fmaf(cv, wv[s], acc[i][s]);
      }
    }
  }

  for (int i = 0; i < 2; ++i){
    int r = rg * 2 + i;
    float* op = out + (size_t)(R0 + r) * 128 + og * 8;
    *(float4*)(op)     = make_float4(acc[i][0]+Wb[og*8+0], acc[i][1]+Wb[og*8+1], acc[i][2]+Wb[og*8+2], acc[i][3]+Wb[og*8+3]);
    *(float4*)(op + 4) = make_float4(acc[i][4]+Wb[og*8+4], acc[i][5]+Wb[og*8+5], acc[i][6]+Wb[og*8+6], acc[i][7]+Wb[og*8+7]);
  }
}

extern "C" void kernel_launch(void* const* d_in, const int* in_sizes, int n_in,
                              void* d_out, int out_size, void* d_ws, size_t ws_size,
                              hipStream_t stream) {
  const float* hA  = (const float*)d_in[0];
  const float* hB  = (const float*)d_in[1];
  const void* maskv= d_in[2];
  const float* WAw = (const float*)d_in[3];
  const float* WAb = (const float*)d_in[4];
  const float* WBw = (const float*)d_in[5];
  const float* WBb = (const float*)d_in[6];
  const float* aAw = (const float*)d_in[7];
  const float* aAb = (const float*)d_in[8];
  const float* aBw = (const float*)d_in[9];
  const float* aBb = (const float*)d_in[10];
  const float* Ww  = (const float*)d_in[11];
  const float* Wb  = (const float*)d_in[12];

  float* ws   = (float*)d_ws;
  uint4* zF   = (uint4*)ws;           // 131,072 uint4 = 524,288 float slots
  float* EAe  = ws + 524288;          // 65,536
  float* EA01e= ws + 589824;          // 65,536
  u32*  EBh   = (u32*)(ws + 655360);  // 32,768 dwords used (slot 65,536)
  u32*  GBh   = (u32*)(ws + 720896);  // 32,768 dwords used (slot 65,536)
  float* WfB  = ws + 786432;          // 16,384
  float* WtO  = ws + 802816;          // 16,384
  float* vA   = ws + 819200;          // 1,024
  float* vB   = ws + 820224;          // 1,024
  float* cA   = ws + 821248;          // 8
  float* cB   = ws + 821256;          // 8
  u32*  Mb    = (u32*)(ws + 821272);  // 524,288
  float* cat  = ws + 1345560;         // 1,048,576 -> total 2,394,136 floats

  if (ws_size < 2394136ull * 4ull){
    kzero<<<4096, 256, 0, stream>>>((float*)d_out);
    return;
  }

  kfold<<<136, 256, 0, stream>>>(WAw, WAb, WBw, WBb, aAw, aAb, aBw, aBb, Ww,
                                 WfB, WtO, vA, vB, cA, cB);
  kmask<<<2048, 256, 0, stream>>>(maskv, Mb);
  kproj<<<256, 256, 0, stream>>>(hB, WfB, WBb, zF);
  ke   <<<512, 256, 0, stream>>>(hA, hB, vA, vB, cA, cB, EAe, EA01e, EBh, GBh);
  kattn<<<2048, 256, 0, stream>>>(zF, EAe, EA01e, EBh, GBh, Mb, cat);
  kout <<<256, 256, 0, stream>>>(cat, WtO, Wb, (float*)d_out);
}

// Round 15
// 181.665 us; speedup vs baseline: 1.1026x; 1.0041x over previous
//
#include <hip/hip_runtime.h>

typedef unsigned short u16;
typedef unsigned int u32;
typedef unsigned char u8;

typedef _Float16 f16x8 __attribute__((ext_vector_type(8)));   // 8 f16 (4 VGPRs)
typedef _Float16 f16x2 __attribute__((ext_vector_type(2)));   // packed pair
typedef __attribute__((ext_vector_type(4))) float f32x4;

// B=4, NA=NB=2048, IN=128, H=8, DH=16, C=128, OUT=128
// Inputs fp32; mask 32-bit words (self-detected per kmask block); OUTPUT fp32.
// kattn: EB/GB staged in LDS per block (8KB, broadcast reads); zF coalesced
// fragment-major f16; MFMA f32_16x16x32_f16; ones-MFMA rowsums.

__global__ __launch_bounds__(256) void kzero(float* __restrict__ out){
  out[blockIdx.x * 256 + threadIdx.x] = 0.f;
}

// ---------------- mask -> packed bits, encoding self-detected ----------------
__global__ __launch_bounds__(256) void kmask(const void* __restrict__ maskv,
                                             u32* __restrict__ Mb){
  __shared__ int s_aw, s_ab, s_ah;
  int t = threadIdx.x;
  if (t == 0){ s_aw = 1; s_ab = 1; s_ah = 1; }
  __syncthreads();
  {
    const u32* mw = (const u32*)maskv;   // same first 1024 words in every block
    int aw = 1, ah = 1, ab = 1;
    #pragma unroll
    for (int j = 0; j < 4; ++j){
      u32 m = mw[t + 256 * j];
      if (!(m == 0u || m == 1u || m == 0x3F800000u)) aw = 0;
      u32 lo = m & 0xFFFFu, hi = m >> 16;
      if (!((lo == 0u || lo == 1u || lo == 0x3F80u) && (hi == 0u || hi == 1u || hi == 0x3F80u))) ah = 0;
      if (m & ~0x01010101u) ab = 0;
    }
    if (!aw) atomicAnd(&s_aw, 0);
    if (!ah) atomicAnd(&s_ah, 0);
    if (!ab) atomicAnd(&s_ab, 0);
  }
  __syncthreads();
  int Fm = 0;
  if (s_aw) Fm = 0; else if (s_ab) Fm = 1; else if (s_ah) Fm = 2;

  if (Fm == 0){
    int lane = t & 63;
    int wid = blockIdx.x * 4 + (t >> 6);       // 8192 waves
    const u32* mw = (const u32*)maskv;
    size_t base = (size_t)wid * 2048;          // 32 iters x 64 words
    #pragma unroll 4
    for (int i = 0; i < 32; ++i){
      u32 v = mw[base + i * 64 + lane];
      unsigned long long bal = __ballot(v != 0u);
      if (lane < 2) Mb[(base + i * 64) / 32 + lane] = (u32)(bal >> (32 * lane));
    }
    return;
  }
  int oid = blockIdx.x * 256 + t;              // one packed word per thread
  u32 bits = 0;
  if (Fm == 1){
    const uint4* mp = (const uint4*)maskv + (size_t)oid * 2;
    #pragma unroll
    for (int k = 0; k < 2; ++k){
      uint4 v = mp[k];
      u32 w[4] = {v.x, v.y, v.z, v.w};
      #pragma unroll
      for (int q = 0; q < 4; ++q)
        #pragma unroll
        for (int bb = 0; bb < 4; ++bb)
          bits |= ((w[q] >> (8*bb)) & 255u ? 1u : 0u) << (k*16 + q*4 + bb);
    }
  } else {
    const uint4* mp = (const uint4*)maskv + (size_t)oid * 4;
    #pragma unroll
    for (int k = 0; k < 4; ++k){
      uint4 v = mp[k];
      u32 w[4] = {v.x, v.y, v.z, v.w};
      #pragma unroll
      for (int q = 0; q < 4; ++q){
        bits |= ((w[q] & 0xFFFFu) ? 1u : 0u) << (k*8 + q*2);
        bits |= ((w[q] >> 16)     ? 1u : 0u) << (k*8 + q*2 + 1);
      }
    }
  }
  Mb[oid] = bits;
}

// ---------------- fold weights ----------------
__global__ __launch_bounds__(256) void kfold(const float* __restrict__ WA, const float* __restrict__ WAb,
                                             const float* __restrict__ WB, const float* __restrict__ WBb,
                                             const float* __restrict__ aAw, const float* __restrict__ aAb,
                                             const float* __restrict__ aBw, const float* __restrict__ aBb,
                                             const float* __restrict__ W,
                                             float* __restrict__ WfB, float* __restrict__ WtO,
                                             float* __restrict__ vA, float* __restrict__ vB,
                                             float* __restrict__ cA, float* __restrict__ cB){
  int gid = blockIdx.x, t = threadIdx.x;
  if (gid < 64){
    int idx = gid * 256 + t;
    int k = idx >> 7, c = idx & 127;
    WfB[idx] = WB[(c >> 4) * 2048 + k * 16 + (c & 15)];
  } else if (gid < 128){
    int idx = (gid - 64) * 256 + t;
    int c = idx >> 7, o = idx & 127;
    WtO[idx] = W[o * 128 + c];
  } else {
    int h = gid - 128;
    if (t < 128){
      float s = 0.f;
      #pragma unroll
      for (int d = 0; d < 16; ++d) s += WA[h * 2048 + t * 16 + d] * aAw[h * 16 + d];
      vA[h * 128 + t] = s;
    } else {
      int i = t - 128;
      float s = 0.f;
      #pragma unroll
      for (int d = 0; d < 16; ++d) s += WB[h * 2048 + i * 16 + d] * aBw[h * 16 + d];
      vB[h * 128 + i] = s;
    }
    if (t == 0){
      float s = aAb[h];
      #pragma unroll
      for (int d = 0; d < 16; ++d) s += WAb[h * 16 + d] * aAw[h * 16 + d];
      cA[h] = s;
    }
    if (t == 255){
      float s = aBb[h];
      #pragma unroll
      for (int d = 0; d < 16; ++d) s += WBb[h * 16 + d] * aBw[h * 16 + d];
      cB[h] = s;
    }
  }
}

// ---------------- projection -> fragment-major f16 zF ----------------
__global__ __launch_bounds__(256) void kproj(const float* __restrict__ hB,
                                             const float* __restrict__ WfB,
                                             const float* __restrict__ bB,
                                             uint4* __restrict__ zF){
  __shared__ float h_l[32 * 132];
  __shared__ float W_l[64 * 128];
  __shared__ float T[128 * 33];     // [channel c][local m]
  int R0 = blockIdx.x * 32;
  int t = threadIdx.x;

  for (int j = 0; j < 4; ++j){
    int idx4 = t + 256 * j;
    int r = idx4 >> 5, k0 = (idx4 & 31) * 4;
    *(float4*)&h_l[r * 132 + k0] = *(const float4*)&hB[(size_t)(R0 + r) * 128 + k0];
  }

  int cg = t & 15, rg = t >> 4;
  float acc[2][8];
  for (int i = 0; i < 2; ++i) for (int s = 0; s < 8; ++s) acc[i][s] = 0.f;

  for (int kc = 0; kc < 2; ++kc){
    __syncthreads();
    for (int j = 0; j < 8; ++j){
      int idx4 = t + 256 * j;
      int k = idx4 >> 5, c0 = (idx4 & 31) * 4;
      *(float4*)&W_l[k * 128 + c0] = *(const float4*)&WfB[(kc * 64 + k) * 128 + c0];
    }
    __syncthreads();
    for (int k = 0; k < 64; ++k){
      int kk = kc * 64 + k;
      float4 w0 = *(const float4*)&W_l[k * 128 + cg * 8];
      float4 w1 = *(const float4*)&W_l[k * 128 + cg * 8 + 4];
      float wv[8] = {w0.x, w0.y, w0.z, w0.w, w1.x, w1.y, w1.z, w1.w};
      #pragma unroll
      for (int i = 0; i < 2; ++i){
        float hv = h_l[(rg * 2 + i) * 132 + kk];
        #pragma unroll
        for (int s = 0; s < 8; ++s) acc[i][s] = fmaf(hv, wv[s], acc[i][s]);
      }
    }
  }

  for (int i = 0; i < 2; ++i)
    #pragma unroll
    for (int s = 0; s < 8; ++s)
      T[(cg * 8 + s) * 33 + rg * 2 + i] = acc[i][s] + bB[cg * 8 + s];
  __syncthreads();

  // fragment-major store: item = (h, lane); 16B = f16 z[d=lane&15][mq..mq+8]
  int b = R0 >> 11;
  int mblk = (R0 & 2047) >> 5;
  for (int it = t; it < 512; it += 256){
    int h = it >> 6, lane = it & 63;
    int d = lane & 15, mq = (lane >> 4) * 8;
    const float* Tp = &T[(h * 16 + d) * 33 + mq];
    u32 wv[4];
    #pragma unroll
    for (int p = 0; p < 4; ++p){
      union { f16x2 h2; u32 u; } c;
      c.h2 = (f16x2){(_Float16)Tp[p * 2], (_Float16)Tp[p * 2 + 1]};
      wv[p] = c.u;
    }
    zF[((size_t)((b * 8 + h) * 64) + mblk) * 64 + lane] = make_uint4(wv[0], wv[1], wv[2], wv[3]);
  }
}

// ---------------- logits -> exp tables ----------------
// A side: fp32 EAe/EA01e. B side: packed f16 pair tables EBh/GBh.
__global__ __launch_bounds__(256) void ke(const float* __restrict__ hA, const float* __restrict__ hB,
                                          const float* __restrict__ vA, const float* __restrict__ vB,
                                          const float* __restrict__ cA, const float* __restrict__ cB,
                                          float* __restrict__ EAe, float* __restrict__ EA01e,
                                          u32* __restrict__ EBh, u32* __restrict__ GBh){
  __shared__ float h_l[32 * 132];
  __shared__ float v_l[8 * 132];
  __shared__ float c_l[8];
  int gid = blockIdx.x, t = threadIdx.x;
  int X = gid >> 8;
  int r0 = (gid & 255) * 32;
  const float* hp = X ? hB : hA;
  const float* vp = X ? vB : vA;
  const float* cp = X ? cB : cA;

  for (int j = 0; j < 4; ++j){
    int idx4 = t + 256 * j;
    int r = idx4 >> 5, k0 = (idx4 & 31) * 4;
    *(float4*)&h_l[r * 132 + k0] = *(const float4*)&hp[(size_t)(r0 + r) * 128 + k0];
  }
  { int hh = t >> 5, k0 = (t & 31) * 4;
    *(float4*)&v_l[hh * 132 + k0] = *(const float4*)&vp[hh * 128 + k0]; }
  if (t < 8) c_l[t] = cp[t];
  __syncthreads();

  int r = t >> 3, h = t & 7;
  float acc = c_l[h];
  #pragma unroll
  for (int k0 = 0; k0 < 128; k0 += 4){
    float4 hv = *(const float4*)&h_l[r * 132 + k0];
    float4 vv = *(const float4*)&v_l[h * 132 + k0];
    acc = fmaf(hv.x, vv.x, acc); acc = fmaf(hv.y, vv.y, acc);
    acc = fmaf(hv.z, vv.z, acc); acc = fmaf(hv.w, vv.w, acc);
  }
  int row = r0 + r;
  int b = row >> 11, n = row & 2047;
  float e0 = __expf(acc), e1 = __expf(0.01f * acc);
  if (X){
    // pair partner (n xor 1) lives at lane xor 8 (r parity = lane bit 3)
    float p0 = __shfl_xor(e0, 8, 64);
    float p1 = __shfl_xor(e1, 8, 64);
    if ((((t & 63) >> 3) & 1) == 0){
      union { f16x2 h2; u32 u; } c0, c1;
      c0.h2 = (f16x2){(_Float16)e0, (_Float16)p0};
      c1.h2 = (f16x2){(_Float16)e1, (_Float16)p1};
      u32 di = (u32)((b * 8 + h) * 1024 + (n >> 1));
      EBh[di] = c0.u;
      GBh[di] = c1.u;
    }
  } else {
    size_t idx = (size_t)(b * 8 + h) * 2048 + n;
    EAe[idx] = e0; EA01e[idx] = e1;
  }
}

// ---------------- attention: f16 MFMA flash, LDS-staged EB/GB, m-split x4 ----------------
__global__ __launch_bounds__(256) void kattn(const uint4* __restrict__ zF,
                                             const float* __restrict__ EAe, const float* __restrict__ EA01e,
                                             const u32* __restrict__ EBh, const u32* __restrict__ GBh,
                                             const u32* __restrict__ Mb,
                                             float* __restrict__ cat){
  __shared__ u32 EB_l[1024];         // full head: 2048 m as 1024 f16-pairs
  __shared__ u32 GB_l[1024];
  __shared__ float red[3][32][17];   // [source wave-1][local row][16 cols + L]
  int t = threadIdx.x;
  int w = t >> 6, lane = t & 63;     // w = m-quarter
  int gid = blockIdx.x;              // 2048
  int h  = gid & 7;
  int nt = (gid >> 3) & 63;
  int b  = gid >> 9;
  int n0 = nt * 32;
  int nl = lane & 15, q = lane >> 4, qs = q * 8;

  // stage EB/GB for this head: 4KB + 4KB, one uint4 per thread each
  {
    const uint4* src0 = (const uint4*)(EBh + (size_t)(b * 8 + h) * 1024);
    const uint4* src1 = (const uint4*)(GBh + (size_t)(b * 8 + h) * 1024);
    ((uint4*)EB_l)[t] = src0[t];
    ((uint4*)GB_l)[t] = src1[t];
  }

  size_t ebase = (size_t)(b * 8 + h) * 2048;
  _Float16 ea0h  = (_Float16)EAe  [ebase + n0 + nl];
  _Float16 ea0sh = (_Float16)EA01e[ebase + n0 + nl];
  _Float16 ea1h  = (_Float16)EAe  [ebase + n0 + 16 + nl];
  _Float16 ea1sh = (_Float16)EA01e[ebase + n0 + 16 + nl];
  f16x2 ea0_2  = (f16x2){ea0h,  ea0h};
  f16x2 ea0s_2 = (f16x2){ea0sh, ea0sh};
  f16x2 ea1_2  = (f16x2){ea1h,  ea1h};
  f16x2 ea1s_2 = (f16x2){ea1sh, ea1sh};

  const u32* EBq = EB_l + w * 256;    // this wave's quarter (LDS)
  const u32* GBq = GB_l + w * 256;
  const uint4* zFp = zF + ((size_t)(b * 8 + h) * 64 + w * 16) * 64 + lane;  // coalesced
  const u32*  mp0 = Mb + ((size_t)(b * 2048) + n0 + nl) * 64 + w * 16;
  const u32*  mp1 = mp0 + 16 * 64;

  f32x4 acc0 = {0.f,0.f,0.f,0.f}, acc1 = {0.f,0.f,0.f,0.f};
  f32x4 lcc0 = {0.f,0.f,0.f,0.f}, lcc1 = {0.f,0.f,0.f,0.f};
  union { u32 u[4]; f16x8 v; } onesu;
  onesu.u[0] = 0x3C003C00u; onesu.u[1] = 0x3C003C00u;
  onesu.u[2] = 0x3C003C00u; onesu.u[3] = 0x3C003C00u;
  const f16x8 ones = onesu.v;

  __syncthreads();                    // staging complete

  uint4 Azu, Bzu; u32 Am0, Am1, Bm0, Bm1;
  #define LOADA(sp) do{ Azu = zFp[(size_t)(sp) * 64]; Am0 = mp0[sp]; Am1 = mp1[sp]; }while(0)
  #define LOADB(sp) do{ Bzu = zFp[(size_t)(sp) * 64]; Bm0 = mp0[sp]; Bm1 = mp1[sp]; }while(0)
  #define COMP(sp,ZU_,M0_,M1_) do{ \
    uint4 EB_ = *(const uint4*)(EBq + (sp) * 16 + q * 4); \
    uint4 GB_ = *(const uint4*)(GBq + (sp) * 16 + q * 4); \
    u32 mb0 = (M0_) >> qs, mb1 = (M1_) >> qs; \
    u32 ebu[4] = {EB_.x, EB_.y, EB_.z, EB_.w}; \
    u32 gbu[4] = {GB_.x, GB_.y, GB_.z, GB_.w}; \
    union { u32 u[4]; f16x8 v; } a0, a1; \
    _Pragma("unroll") \
    for (int p = 0; p < 4; ++p){ \
      int j0 = 2*p, j1 = 2*p + 1; \
      u32 k00 = (u32)(((int)(mb0 << (31 - j0))) >> 31); \
      u32 k01 = (u32)(((int)(mb0 << (31 - j1))) >> 31); \
      u32 k10 = (u32)(((int)(mb1 << (31 - j0))) >> 31); \
      u32 k11 = (u32)(((int)(mb1 << (31 - j1))) >> 31); \
      u32 kc0 = __builtin_amdgcn_perm(k01, k00, 0x05040100u); \
      u32 kc1 = __builtin_amdgcn_perm(k11, k10, 0x05040100u); \
      union { u32 u; f16x2 h2; } eb, gb, r0u, r1u; \
      eb.u = ebu[p]; gb.u = gbu[p]; \
      r0u.h2 = __builtin_elementwise_max(ea0_2 * eb.h2, ea0s_2 * gb.h2); \
      r1u.h2 = __builtin_elementwise_max(ea1_2 * eb.h2, ea1s_2 * gb.h2); \
      a0.u[p] = r0u.u & kc0; \
      a1.u[p] = r1u.u & kc1; \
    } \
    union { uint4 u; f16x8 v; } zu; zu.u = ZU_; \
    acc0 = __builtin_amdgcn_mfma_f32_16x16x32_f16(a0.v, zu.v, acc0, 0, 0, 0); \
    lcc0 = __builtin_amdgcn_mfma_f32_16x16x32_f16(a0.v, ones, lcc0, 0, 0, 0); \
    acc1 = __builtin_amdgcn_mfma_f32_16x16x32_f16(a1.v, zu.v, acc1, 0, 0, 0); \
    lcc1 = __builtin_amdgcn_mfma_f32_16x16x32_f16(a1.v, ones, lcc1, 0, 0, 0); }while(0)

  LOADA(0);
  LOADB(1);
  #pragma unroll 4
  for (int s = 0; s < 16; s += 2){
    COMP(s, Azu, Am0, Am1);
    LOADA(s + 2);                        // <=2-step overrun stays inside ws
    COMP(s + 1, Bzu, Bm0, Bm1);
    LOADB(s + 3);
  }
  #undef LOADA
  #undef LOADB
  #undef COMP

  if (w > 0){
    #pragma unroll
    for (int r = 0; r < 4; ++r){
      int row = q * 4 + r;
      red[w - 1][row][nl]      = acc0[r];
      red[w - 1][row + 16][nl] = acc1[r];
    }
    if (nl == 0){
      #pragma unroll
      for (int r = 0; r < 4; ++r){
        red[w - 1][q * 4 + r][16]      = lcc0[r];
        red[w - 1][q * 4 + r + 16][16] = lcc1[r];
      }
    }
  }
  __syncthreads();
  if (w == 0){
    #pragma unroll
    for (int r = 0; r < 4; ++r){
      int row = q * 4 + r;
      float a0 = acc0[r] + red[0][row][nl]      + red[1][row][nl]      + red[2][row][nl];
      float a1 = acc1[r] + red[0][row + 16][nl] + red[1][row + 16][nl] + red[2][row + 16][nl];
      float L0 = lcc0[r] + red[0][row][16]      + red[1][row][16]      + red[2][row][16];
      float L1 = lcc1[r] + red[0][row + 16][16] + red[1][row + 16][16] + red[2][row + 16][16];
      float r0 = (L0 > 0.f) ? 1.f / L0 : 0.f;
      float r1 = (L1 > 0.f) ? 1.f / L1 : 0.f;
      cat[((size_t)(b * 2048) + n0 + row)      * 128 + h * 16 + nl] = a0 * r0;
      cat[((size_t)(b * 2048) + n0 + 16 + row) * 128 + h * 16 + nl] = a1 * r1;
    }
  }
}

// ---------------- output GEMM: out = cat @ WtO + Wb ----------------
__global__ __launch_bounds__(256) void kout(const float* __restrict__ cat,
                                            const float* __restrict__ WtO, const float* __restrict__ Wb,
                                            float* __restrict__ out){
  __shared__ float cat_l[32 * 132];
  __shared__ float Wt_l[64 * 128];
  int R0 = blockIdx.x * 32;
  int t = threadIdx.x;

  for (int jj = 0; jj < 4; ++jj){
    int idx4 = t + 256 * jj;
    int r = idx4 >> 5, c0 = (idx4 & 31) * 4;
    *(float4*)&cat_l[r * 132 + c0] = *(const float4*)&cat[((size_t)R0 + r) * 128 + c0];
  }

  int og = t & 15, rg = t >> 4;
  float acc[2][8];
  for (int i = 0; i < 2; ++i) for (int s = 0; s < 8; ++s) acc[i][s] = 0.f;

  for (int kc = 0; kc < 2; ++kc){
    __syncthreads();
    for (int j = 0; j < 8; ++j){
      int idx4 = t + 256 * j;
      int k = idx4 >> 5, o0 = (idx4 & 31) * 4;
      *(float4*)&Wt_l[k * 128 + o0] = *(const float4*)&WtO[(kc * 64 + k) * 128 + o0];
    }
    __syncthreads();
    for (int k = 0; k < 64; ++k){
      int kk = kc * 64 + k;
      float4 w0 = *(const float4*)&Wt_l[k * 128 + og * 8];
      float4 w1 = *(const float4*)&Wt_l[k * 128 + og * 8 + 4];
      float wv[8] = {w0.x, w0.y, w0.z, w0.w, w1.x, w1.y, w1.z, w1.w};
      #pragma unroll
      for (int i = 0; i < 2; ++i){
        float cv = cat_l[(rg * 2 + i) * 132 + kk];
        #pragma unroll
        for (int s = 0; s < 8; ++s) acc[i][s] = fmaf(cv, wv[s], acc[i][s]);
      }
    }
  }

  for (int i = 0; i < 2; ++i){
    int r = rg * 2 + i;
    float* op = out + (size_t)(R0 + r) * 128 + og * 8;
    *(float4*)(op)     = make_float4(acc[i][0]+Wb[og*8+0], acc[i][1]+Wb[og*8+1], acc[i][2]+Wb[og*8+2], acc[i][3]+Wb[og*8+3]);
    *(float4*)(op + 4) = make_float4(acc[i][4]+Wb[og*8+4], acc[i][5]+Wb[og*8+5], acc[i][6]+Wb[og*8+6], acc[i][7]+Wb[og*8+7]);
  }
}

extern "C" void kernel_launch(void* const* d_in, const int* in_sizes, int n_in,
                              void* d_out, int out_size, void* d_ws, size_t ws_size,
                              hipStream_t stream) {
  const float* hA  = (const float*)d_in[0];
  const float* hB  = (const float*)d_in[1];
  const void* maskv= d_in[2];
  const float* WAw = (const float*)d_in[3];
  const float* WAb = (const float*)d_in[4];
  const float* WBw = (const float*)d_in[5];
  const float* WBb = (const float*)d_in[6];
  const float* aAw = (const float*)d_in[7];
  const float* aAb = (const float*)d_in[8];
  const float* aBw = (const float*)d_in[9];
  const float* aBb = (const float*)d_in[10];
  const float* Ww  = (const float*)d_in[11];
  const float* Wb  = (const float*)d_in[12];

  float* ws   = (float*)d_ws;
  uint4* zF   = (uint4*)ws;           // 131,072 uint4 = 524,288 float slots
  float* EAe  = ws + 524288;          // 65,536
  float* EA01e= ws + 589824;          // 65,536
  u32*  EBh   = (u32*)(ws + 655360);  // 32,768 dwords used (slot 65,536)
  u32*  GBh   = (u32*)(ws + 720896);  // 32,768 dwords used (slot 65,536)
  float* WfB  = ws + 786432;          // 16,384
  float* WtO  = ws + 802816;          // 16,384
  float* vA   = ws + 819200;          // 1,024
  float* vB   = ws + 820224;          // 1,024
  float* cA   = ws + 821248;          // 8
  float* cB   = ws + 821256;          // 8
  u32*  Mb    = (u32*)(ws + 821272);  // 524,288
  float* cat  = ws + 1345560;         // 1,048,576 -> total 2,394,136 floats

  if (ws_size < 2394136ull * 4ull){
    kzero<<<4096, 256, 0, stream>>>((float*)d_out);
    return;
  }

  kfold<<<136, 256, 0, stream>>>(WAw, WAb, WBw, WBb, aAw, aAb, aBw, aBb, Ww,
                                 WfB, WtO, vA, vB, cA, cB);
  kmask<<<2048, 256, 0, stream>>>(maskv, Mb);
  kproj<<<256, 256, 0, stream>>>(hB, WfB, WBb, zF);
  ke   <<<512, 256, 0, stream>>>(hA, hB, vA, vB, cA, cB, EAe, EA01e, EBh, GBh);
  kattn<<<2048, 256, 0, stream>>>(zF, EAe, EA01e, EBh, GBh, Mb, cat);
  kout <<<256, 256, 0, stream>>>(cat, WtO, Wb, (float*)d_out);
}